// Round 1
// baseline (167.481 us; speedup 1.0000x reference)
//
#include <hip/hip_runtime.h>

// VectorQuantizer: x [32768 x 64] fp32, embeddings [64 x 1024] fp32.
// out = quantized (straight-through: x + (q - x)), loss = 0.25*m + m,
// m = mean((q-x)^2). d_out = [out (2097152 floats), loss (1 float)].

#define NROWS 32768
#define DDIM  64
#define KCODE 1024
#define NELEM (NROWS * DDIM)   // 2097152

// ws layout (floats):
//   ws[0]            : loss accumulator (memset to 0 each launch)
//   ws[256 .. 256+K) : Se[k] = sum_d e[d][k]^2
//   ws[2048 .. +K*D) : eT[k][d] transposed embeddings (for contiguous gather)

__global__ void vq_prep(const float* __restrict__ e,
                        float* __restrict__ se,
                        float* __restrict__ eT) {
    int k = blockIdx.x * blockDim.x + threadIdx.x;  // 0..1023
    float s = 0.f;
    #pragma unroll
    for (int d = 0; d < DDIM; ++d) {
        float v = e[d * KCODE + k];
        s = fmaf(v, v, s);
        eT[k * DDIM + d] = v;
    }
    se[k] = s;
}

__launch_bounds__(512)
__global__ void vq_main(const float* __restrict__ x,
                        const float* __restrict__ e,
                        const float* __restrict__ se,
                        const float* __restrict__ eT,
                        float* __restrict__ out,
                        float* __restrict__ lossAcc) {
    const int lane = threadIdx.x & 63;
    const int wave = __builtin_amdgcn_readfirstlane(threadIdx.x >> 6);  // 0..7
    const int row  = blockIdx.x * 64 + lane;

    // Load this lane's x row into registers (64 VGPRs).
    float xr[DDIM];
    const float4* xp = (const float4*)(x + (size_t)row * DDIM);
    #pragma unroll
    for (int i = 0; i < 16; ++i) {
        float4 v = xp[i];
        xr[4*i+0] = v.x; xr[4*i+1] = v.y; xr[4*i+2] = v.z; xr[4*i+3] = v.w;
    }
    float sx = 0.f;
    #pragma unroll
    for (int d = 0; d < DDIM; ++d) sx = fmaf(xr[d], xr[d], sx);

    // Each wave scans a 128-code chunk; e addresses are wave-uniform -> s_load.
    const int kBase = wave * (KCODE / 8);
    float best = 3.4e38f;
    int  bidx = kBase;

    for (int kk = 0; kk < KCODE / 8; kk += 4) {
        float dot0 = 0.f, dot1 = 0.f, dot2 = 0.f, dot3 = 0.f;
        const float* ep = e + kBase + kk;   // uniform base
        #pragma unroll
        for (int d = 0; d < DDIM; ++d) {
            float xd = xr[d];
            dot0 = fmaf(xd, ep[d * KCODE + 0], dot0);
            dot1 = fmaf(xd, ep[d * KCODE + 1], dot1);
            dot2 = fmaf(xd, ep[d * KCODE + 2], dot2);
            dot3 = fmaf(xd, ep[d * KCODE + 3], dot3);
        }
        // dist = (Sx + Se_k) - 2*dot, same association as the reference.
        const float* sp = se + kBase + kk;
        float t0 = sx + sp[0]; float d0 = t0 - 2.0f * dot0;
        float t1 = sx + sp[1]; float d1 = t1 - 2.0f * dot1;
        float t2 = sx + sp[2]; float d2 = t2 - 2.0f * dot2;
        float t3 = sx + sp[3]; float d3 = t3 - 2.0f * dot3;
        // strict <, ascending k => first-index tie-break like np.argmin
        if (d0 < best) { best = d0; bidx = kBase + kk + 0; }
        if (d1 < best) { best = d1; bidx = kBase + kk + 1; }
        if (d2 < best) { best = d2; bidx = kBase + kk + 2; }
        if (d3 < best) { best = d3; bidx = kBase + kk + 3; }
    }

    // Combine the 8 waves' candidates per row (ascending chunk order keeps
    // first-index tie-break).
    __shared__ float lbest[8][64];
    __shared__ int   lidx[8][64];
    lbest[wave][lane] = best;
    lidx[wave][lane]  = bidx;
    __syncthreads();

    if (threadIdx.x < 64) {
        float b  = lbest[0][lane];
        int   bi = lidx[0][lane];
        #pragma unroll
        for (int w = 1; w < 8; ++w) {
            float bw = lbest[w][lane];
            int   iw = lidx[w][lane];
            if (bw < b) { b = bw; bi = iw; }
        }

        // Gather code vector (contiguous in eT), write out = x + (q - x),
        // accumulate (q - x)^2.
        const float4* qp = (const float4*)(eT + (size_t)bi * DDIM);
        float4* op = (float4*)(out + (size_t)row * DDIM);
        float lsum = 0.f;
        #pragma unroll
        for (int i = 0; i < 16; ++i) {
            float4 q = qp[i];
            float4 o;
            float dx;
            dx = q.x - xr[4*i+0]; o.x = xr[4*i+0] + dx; lsum = fmaf(dx, dx, lsum);
            dx = q.y - xr[4*i+1]; o.y = xr[4*i+1] + dx; lsum = fmaf(dx, dx, lsum);
            dx = q.z - xr[4*i+2]; o.z = xr[4*i+2] + dx; lsum = fmaf(dx, dx, lsum);
            dx = q.w - xr[4*i+3]; o.w = xr[4*i+3] + dx; lsum = fmaf(dx, dx, lsum);
            op[i] = o;
        }

        // wave-64 reduction of lsum
        #pragma unroll
        for (int off = 32; off > 0; off >>= 1)
            lsum += __shfl_down(lsum, off, 64);
        if (lane == 0) atomicAdd(lossAcc, lsum);
    }
}

__global__ void vq_loss(const float* __restrict__ lossAcc,
                        float* __restrict__ out) {
    float m = lossAcc[0] / (float)NELEM;   // exact pow2 divide
    out[NELEM] = 0.25f * m + m;            // beta*m + m, same assoc as ref
}

extern "C" void kernel_launch(void* const* d_in, const int* in_sizes, int n_in,
                              void* d_out, int out_size, void* d_ws, size_t ws_size,
                              hipStream_t stream) {
    const float* x = (const float*)d_in[0];
    const float* e = (const float*)d_in[1];
    float* out = (float*)d_out;
    float* ws  = (float*)d_ws;

    float* lossAcc = ws;
    float* se      = ws + 256;
    float* eT      = ws + 2048;

    hipMemsetAsync(d_ws, 0, sizeof(float), stream);
    vq_prep<<<4, 256, 0, stream>>>(e, se, eT);
    vq_main<<<NROWS / 64, 512, 0, stream>>>(x, e, se, eT, out, lossAcc);
    vq_loss<<<1, 1, 0, stream>>>(lossAcc, out);
}